// Round 1
// baseline (152.250 us; speedup 1.0000x reference)
//
#include <hip/hip_runtime.h>

// ---------------------------------------------------------------------------
// Convnet: 8 overlapping sections, conv [32x16] x 128 ch, threshold 15, pool
// (400,16), winner-take-all -> single channel index.
//
// k1 (prep):   W fp32 -> bf16, repacked pack-major for global_load_lds; zero pool
// k2 (conv):   implicit-im2col MFMA GEMM per (s, t-tile, fo-tile); threshold+OR
//              in-register -> pool bits [8][128][15]
// k3 (winner): reference get_k_winners logic on 15360 pool bits -> d_out
// ---------------------------------------------------------------------------

using short8 = __attribute__((ext_vector_type(8))) short;
using f32x4  = __attribute__((ext_vector_type(4))) float;

__device__ __forceinline__ unsigned short f2bf(float f) {
  unsigned u = __float_as_uint(f);
  u += 0x7FFFu + ((u >> 16) & 1u);   // RNE
  return (unsigned short)(u >> 16);
}

#define THRESH 15.0f

// ---------------- prep: Wp[((s*64+p)*128 + c)*8 + e] = bf16(W[s][c][k=p*8+e])
__global__ __launch_bounds__(256) void prep_kernel(const float* __restrict__ W,
                                                   unsigned short* __restrict__ Wp,
                                                   int* __restrict__ pool) {
  int t = blockIdx.x * 256 + threadIdx.x;   // 65536 threads
  if (t < 15360) pool[t] = 0;
  int s = t >> 13;
  int r = t & 8191;
  int c = r >> 6;
  int p = r & 63;
  const float* src = W + ((s * 128 + c) * 512 + p * 8);
  float4 v0 = *(const float4*)(src);
  float4 v1 = *(const float4*)(src + 4);
  short8 o;
  o[0] = (short)f2bf(v0.x); o[1] = (short)f2bf(v0.y);
  o[2] = (short)f2bf(v0.z); o[3] = (short)f2bf(v0.w);
  o[4] = (short)f2bf(v1.x); o[5] = (short)f2bf(v1.y);
  o[6] = (short)f2bf(v1.z); o[7] = (short)f2bf(v1.w);
  *(short8*)(Wp + ((s * 64 + p) * 128 + c) * 8) = o;
}

// ---------------- conv + threshold + pool-OR
// grid: 8 s * 25 t-tiles * 30 fo-tiles = 6000 blocks, 256 threads (4 waves)
// M = 128 (16 t x 8 fo), N = 128 ch, K = 512 (kt*16+kf)
__global__ __launch_bounds__(256) void conv_pool_kernel(const float* __restrict__ X,
                                                        const unsigned short* __restrict__ Wp,
                                                        int* __restrict__ pool) {
  // 8 fo-shifted copies of the X patch: copy d holds cols fo0+d .. fo0+d+15,
  // rows 0..46, row stride padded to 24 (48 B: keeps b128 16B-aligned, <=2-way banks)
  __shared__ __align__(16) unsigned short Ash[8 * 1128];   // 18048 B
  __shared__ __align__(16) unsigned short Bsh[8192];       // 16384 B: 8 packs x 128 ch x 8
  __shared__ unsigned poolbits[16];

  const int tid = threadIdx.x;
  const int bid = blockIdx.x;
  const int s   = bid / 750;
  const int rem = bid % 750;
  const int tt  = rem / 30;
  const int ft  = rem % 30;
  const int t0 = tt * 16, fo0 = ft * 8, fp = ft >> 1;
  const int srow = s * 400 + t0;             // first X row used

  if (tid < 16) poolbits[tid] = 0;

  // ---- stage A copies (fp32 global -> bf16 LDS), 8*47*16 = 6016 elems
  for (int i = tid; i < 6016; i += 256) {
    int d = i / 752, j = i % 752;
    int r = j >> 4, cc = j & 15;
    float v = X[(srow + r) * 256 + fo0 + d + cc];
    Ash[d * 1128 + r * 24 + cc] = f2bf(v);
  }

  f32x4 acc[2][8];
#pragma unroll
  for (int a = 0; a < 2; ++a)
#pragma unroll
    for (int b = 0; b < 8; ++b) acc[a][b] = (f32x4){0.f, 0.f, 0.f, 0.f};

  const int w = tid >> 6, l = tid & 63;
  const int li = l & 15, q = l >> 4;
  const int mt0 = w * 2;                      // wave handles fo offsets mt0, mt0+1

  const unsigned short* wbase = Wp + s * 65536;   // 64 packs * 128 ch * 8

  __syncthreads();   // A copies + poolbits ready

  for (int ch = 0; ch < 8; ++ch) {            // K chunks of 64
    const unsigned short* gsrc = wbase + ch * 8192;
#pragma unroll
    for (int it = 0; it < 4; ++it) {
      int off = (it * 256 + tid) * 8;         // elems; lane*16B contiguous per wave
      __builtin_amdgcn_global_load_lds(
          (const __attribute__((address_space(1))) void*)(gsrc + off),
          (__attribute__((address_space(3))) void*)(&Bsh[off]), 16, 0, 0);
    }
    __syncthreads();

#pragma unroll
    for (int kb = 0; kb < 2; ++kb) {
      // A frag: lane holds A[m=li][k=q*8+j]; k -> kt = ch*4+kb*2+(q>>1), kf = (q&1)*8+j
      const int rowb = (ch * 4 + kb * 2 + (q >> 1)) + li;
      const int colo = (q & 1) * 8;
      short8 a0 = *(const short8*)&Ash[(mt0)     * 1128 + rowb * 24 + colo];
      short8 a1 = *(const short8*)&Ash[(mt0 + 1) * 1128 + rowb * 24 + colo];
#pragma unroll
      for (int nt = 0; nt < 8; ++nt) {
        // B frag: lane holds B[k=q*8+j][n=li]; pack = kb*4+q
        short8 bfr = *(const short8*)&Bsh[((kb * 4 + q) * 128 + nt * 16 + li) * 8];
        acc[0][nt] = __builtin_amdgcn_mfma_f32_16x16x32_bf16(a0, bfr, acc[0][nt], 0, 0, 0);
        acc[1][nt] = __builtin_amdgcn_mfma_f32_16x16x32_bf16(a1, bfr, acc[1][nt], 0, 0, 0);
      }
    }
    __syncthreads();
  }

  // ---- threshold + OR. Lane holds channels c = nt*16 + li (C/D col = lane&15).
  unsigned sp = 0;
#pragma unroll
  for (int nt = 0; nt < 8; ++nt) {
    float m0 = fmaxf(fmaxf(acc[0][nt][0], acc[0][nt][1]),
                     fmaxf(acc[0][nt][2], acc[0][nt][3]));
    float m1 = fmaxf(fmaxf(acc[1][nt][0], acc[1][nt][1]),
                     fmaxf(acc[1][nt][2], acc[1][nt][3]));
    if (fmaxf(m0, m1) >= THRESH) sp |= (1u << nt);
  }
  sp |= __shfl_xor(sp, 16, 64);
  sp |= __shfl_xor(sp, 32, 64);
  if (l < 16 && sp) atomicOr(&poolbits[l], sp);
  __syncthreads();

  if (tid < 128) {
    unsigned bits = poolbits[tid & 15];
    if ((bits >> (tid >> 4)) & 1)
      pool[(s * 128 + tid) * 15 + fp] = 1;   // benign same-value race across blocks
  }
}

// ---------------- winner (reference get_k_winners semantics)
__global__ __launch_bounds__(256) void winner_kernel(const int* __restrict__ pool,
                                                     float* __restrict__ out) {
  __shared__ int sh_v;
  __shared__ int sh_best;
  int tid = threadIdx.x;
  if (tid == 0) { sh_v = 0; sh_best = 0; }
  __syncthreads();

  int localv = 0;
  for (int p = tid; p < 1920; p += 256) {
    int c = p / 15, f = p % 15;
    int cnt = 0;
    for (int s = 0; s < 8; ++s) cnt += pool[(s * 128 + c) * 15 + f];
    if (cnt > 0) {
      int early = 8 - cnt; if (early > 7) early = 7;
      localv |= pool[(early * 128 + c) * 15 + f];
    }
  }
  if (localv) atomicOr(&sh_v, 1);
  __syncthreads();

  const int v = sh_v * 8;   // trunc.max() * T
  int localbest = 0;
  for (int p = tid; p < 1920; p += 256) {
    int c = p / 15, f = p % 15;
    int cnt = 0;
    for (int s = 0; s < 8; ++s) cnt += pool[(s * 128 + c) * 15 + f];
    int early = 8 - cnt; if (early > 7) early = 7;
    int val = pool[(early * 128 + c) * 15 + f];
    int total = cnt * (val + v);
    int pack = (total << 12) | (4095 - p);   // max total, then smallest flat idx
    if (pack > localbest) localbest = pack;
  }
  atomicMax(&sh_best, localbest);
  __syncthreads();

  if (tid == 0) {
    int total = sh_best >> 12;
    int p = 4095 - (sh_best & 4095);
    int feat = p / 15;
    out[0] = (total != 0) ? (float)feat : -1.0f;
  }
}

// ---------------------------------------------------------------------------
extern "C" void kernel_launch(void* const* d_in, const int* in_sizes, int n_in,
                              void* d_out, int out_size, void* d_ws, size_t ws_size,
                              hipStream_t stream) {
  (void)in_sizes; (void)n_in; (void)out_size; (void)ws_size;
  const float* X = (const float*)d_in[0];
  const float* W = (const float*)d_in[1];
  unsigned short* Wp = (unsigned short*)d_ws;              // 1,048,576 B
  int* pool = (int*)((char*)d_ws + (1 << 20));             // 61,440 B

  prep_kernel<<<256, 256, 0, stream>>>(W, Wp, pool);
  conv_pool_kernel<<<6000, 256, 0, stream>>>(X, Wp, pool);
  winner_kernel<<<1, 256, 0, stream>>>(pool, (float*)d_out);
}